// Round 2
// baseline (2405.783 us; speedup 1.0000x reference)
//
#include <hip/hip_runtime.h>
#include <hip/hip_fp16.h>
#include <math.h>

#ifndef M_PI
#define M_PI 3.14159265358979323846
#endif

// ---------------------------------------------------------------------------
// TensorNet interaction, fp32 math, fp16 edge-feature spill.
// Compressed irreducible rep per (n,f): u[9] =
//   { lam, a01, a02, a12, s00, s01, s02, s11, s12 }   (s22 = -s00-s11)
// Slab layout for node tensors: [9][N][F] (F contiguous).
//
// New path (needs ~272 MB ws): CSR-sort edges by src, MLP writes per-edge
// features to sorted rows (fp16), gather kernel accumulates messages in
// registers (NO atomics) and fuses the node-mix stage.
// Fallback path (172.8 MB): round-1 atomic scatter.
// ---------------------------------------------------------------------------

__device__ __forceinline__ float silu_f(float x) {
    return x / (1.0f + __expf(-x));
}

__device__ __forceinline__ void recon(const float u[9], float M[9]) {
    M[0] =  u[0] + u[4];
    M[1] =  u[1] + u[5];
    M[2] =  u[2] + u[6];
    M[3] = -u[1] + u[5];
    M[4] =  u[0] + u[7];
    M[5] =  u[3] + u[8];
    M[6] = -u[2] + u[6];
    M[7] = -u[3] + u[8];
    M[8] =  u[0] - u[4] - u[7];
}

// ---------------------------------------------------------------------------
// K1: per (n,f): Xn = X/(|X|^2+1), decompose -> U slabs [9][N][64]
// ---------------------------------------------------------------------------
__global__ __launch_bounds__(256) void k_node_prep(
    const float* __restrict__ X, float* __restrict__ U, int N)
{
    __shared__ float s_x[2304];
    int tid = threadIdx.x;
    size_t base = (size_t)blockIdx.x * 2304;
    size_t total = (size_t)N * 576;
    for (int idx = tid; idx < 2304; idx += 256) {
        size_t gi = base + idx;
        s_x[idx] = (gi < total) ? X[gi] : 0.f;
    }
    __syncthreads();
    int w = tid >> 6, f = tid & 63;
    int n = blockIdx.x * 4 + w;
    if (n >= N) return;
    float m[9]; float n2 = 0.f;
#pragma unroll
    for (int i = 0; i < 9; ++i) { m[i] = s_x[w * 576 + f * 9 + i]; n2 += m[i] * m[i]; }
    float inv = 1.0f / (n2 + 1.0f);
#pragma unroll
    for (int i = 0; i < 9; ++i) m[i] *= inv;
    float lam = (m[0] + m[4] + m[8]) * (1.f / 3.f);
    size_t slab = (size_t)N * 64;
    size_t t = (size_t)n * 64 + f;
    U[0 * slab + t] = lam;
    U[1 * slab + t] = 0.5f * (m[1] - m[3]);
    U[2 * slab + t] = 0.5f * (m[2] - m[6]);
    U[3 * slab + t] = 0.5f * (m[5] - m[7]);
    U[4 * slab + t] = m[0] - lam;
    U[5 * slab + t] = 0.5f * (m[1] + m[3]);
    U[6 * slab + t] = 0.5f * (m[2] + m[6]);
    U[7 * slab + t] = m[4] - lam;
    U[8 * slab + t] = 0.5f * (m[5] + m[7]);
}

// ---------------------------------------------------------------------------
// Comp GEMM: out[row][g] = sum_f in[row][f] * Wsel[g][f], rows = c*N+n.
// ---------------------------------------------------------------------------
__global__ __launch_bounds__(256) void k_comp_gemm(
    const float* __restrict__ in, float* __restrict__ out,
    const float* __restrict__ Wa, const float* __restrict__ Wb,
    const float* __restrict__ Wc, int R, int N)
{
    __shared__ float s_a[64 * 68];
    int tid = threadIdx.x;
    int r0 = blockIdx.x * 64;
    for (int idx = tid; idx < 1024; idx += 256) {
        int row = idx >> 4;
        int k4 = (idx & 15) << 2;
        int gr = r0 + row;
        float4 v = make_float4(0.f, 0.f, 0.f, 0.f);
        if (gr < R) v = *(const float4*)(in + (size_t)gr * 64 + k4);
        s_a[(k4 + 0) * 68 + row] = v.x;
        s_a[(k4 + 1) * 68 + row] = v.y;
        s_a[(k4 + 2) * 68 + row] = v.z;
        s_a[(k4 + 3) * 68 + row] = v.w;
    }
    __syncthreads();
    int et = tid >> 4, ct = tid & 15;
    int c0 = ct * 4;
    int rbase = r0 + et * 4;
    float4 acc[4];
#pragma unroll
    for (int cc = 0; cc < 4; ++cc) acc[cc] = make_float4(0.f, 0.f, 0.f, 0.f);

    int cA = r0 / N;
    int rlast = min(r0 + 63, R - 1);
    int cB = rlast / N;
    int gA = (cA == 0) ? 0 : (cA < 4 ? 1 : 2);
    int gB = (cB == 0) ? 0 : (cB < 4 ? 1 : 2);

    if (gA == gB) {
        const float* W = (gA == 0) ? Wa : (gA == 1 ? Wb : Wc);
        for (int k = 0; k < 64; k += 4) {
            float4 a0 = *(const float4*)&s_a[(k + 0) * 68 + et * 4];
            float4 a1 = *(const float4*)&s_a[(k + 1) * 68 + et * 4];
            float4 a2 = *(const float4*)&s_a[(k + 2) * 68 + et * 4];
            float4 a3 = *(const float4*)&s_a[(k + 3) * 68 + et * 4];
#pragma unroll
            for (int cc = 0; cc < 4; ++cc) {
                float4 w4 = *(const float4*)&W[(c0 + cc) * 64 + k];
                acc[cc].x += w4.x * a0.x + w4.y * a1.x + w4.z * a2.x + w4.w * a3.x;
                acc[cc].y += w4.x * a0.y + w4.y * a1.y + w4.z * a2.y + w4.w * a3.y;
                acc[cc].z += w4.x * a0.z + w4.y * a1.z + w4.z * a2.z + w4.w * a3.z;
                acc[cc].w += w4.x * a0.w + w4.y * a1.w + w4.z * a2.w + w4.w * a3.w;
            }
        }
    } else {
        const float* Wi[4];
#pragma unroll
        for (int i = 0; i < 4; ++i) {
            int r = min(rbase + i, R - 1);
            int c = r / N;
            int g = (c == 0) ? 0 : (c < 4 ? 1 : 2);
            Wi[i] = (g == 0) ? Wa : (g == 1 ? Wb : Wc);
        }
        for (int k = 0; k < 64; ++k) {
            float a0 = s_a[k * 68 + et * 4 + 0];
            float a1 = s_a[k * 68 + et * 4 + 1];
            float a2 = s_a[k * 68 + et * 4 + 2];
            float a3 = s_a[k * 68 + et * 4 + 3];
#pragma unroll
            for (int cc = 0; cc < 4; ++cc) {
                acc[cc].x += Wi[0][(c0 + cc) * 64 + k] * a0;
                acc[cc].y += Wi[1][(c0 + cc) * 64 + k] * a1;
                acc[cc].z += Wi[2][(c0 + cc) * 64 + k] * a2;
                acc[cc].w += Wi[3][(c0 + cc) * 64 + k] * a3;
            }
        }
    }
    if (rbase + 0 < R) {
        float4 o = make_float4(acc[0].x, acc[1].x, acc[2].x, acc[3].x);
        *(float4*)(out + (size_t)(rbase + 0) * 64 + c0) = o;
    }
    if (rbase + 1 < R) {
        float4 o = make_float4(acc[0].y, acc[1].y, acc[2].y, acc[3].y);
        *(float4*)(out + (size_t)(rbase + 1) * 64 + c0) = o;
    }
    if (rbase + 2 < R) {
        float4 o = make_float4(acc[0].z, acc[1].z, acc[2].z, acc[3].z);
        *(float4*)(out + (size_t)(rbase + 2) * 64 + c0) = o;
    }
    if (rbase + 3 < R) {
        float4 o = make_float4(acc[0].w, acc[1].w, acc[2].w, acc[3].w);
        *(float4*)(out + (size_t)(rbase + 3) * 64 + c0) = o;
    }
}

// ---------------------------------------------------------------------------
// CSR sort of edges by src: histogram -> scan -> ranked placement.
// ---------------------------------------------------------------------------
__global__ __launch_bounds__(256) void k_hist(
    const int* __restrict__ pair, int* __restrict__ count, int E)
{
    int e = blockIdx.x * 256 + threadIdx.x;
    if (e < E) atomicAdd(&count[pair[e]], 1);
}

__global__ __launch_bounds__(1024) void k_scan(
    const int* __restrict__ count, int* __restrict__ off,
    int* __restrict__ cursor, int N, int E)
{
    __shared__ int s[1024];
    __shared__ int s_carry;
    int tid = threadIdx.x;
    if (tid == 0) s_carry = 0;
    __syncthreads();
    for (int base = 0; base < N; base += 1024) {
        int i = base + tid;
        int v = (i < N) ? count[i] : 0;
        s[tid] = v;
        __syncthreads();
        for (int d = 1; d < 1024; d <<= 1) {
            int t = (tid >= d) ? s[tid - d] : 0;
            __syncthreads();
            s[tid] += t;
            __syncthreads();
        }
        int incl = s[tid];
        int excl = s_carry + incl - v;
        if (i < N) { off[i] = excl; cursor[i] = excl; }
        __syncthreads();
        if (tid == 1023) s_carry += s[1023];
        __syncthreads();
    }
    if (tid == 0) off[N] = E;
}

__global__ __launch_bounds__(256) void k_scatter_sort(
    const int* __restrict__ pair, int* __restrict__ cursor,
    int* __restrict__ posOf, int* __restrict__ dstp, int E)
{
    int e = blockIdx.x * 256 + threadIdx.x;
    if (e < E) {
        int s = pair[e];
        int d = pair[(size_t)E + e];
        int pos = atomicAdd(&cursor[s], 1);
        posOf[e] = pos;
        dstp[pos] = d;
    }
}

// ---------------------------------------------------------------------------
// MLP kernel: edge MLP (32->64->128->192, SiLU, x cutoff); writes fp16
// features to sorted row pos[e]: rfvS[pos][cmp*64+f].
// 64 edges/block, 256 threads, activations transposed in LDS [c][68].
// ---------------------------------------------------------------------------
__global__ __launch_bounds__(256) void k_edge_mlp(
    const float* __restrict__ radial, const float* __restrict__ d_ij,
    const int* __restrict__ posOf,
    const float* __restrict__ W1, const float* __restrict__ b1,
    const float* __restrict__ W2, const float* __restrict__ b2,
    const float* __restrict__ W3, const float* __restrict__ b3,
    __half* __restrict__ rfvS, int E)
{
    __shared__ float s_act[192 * 68];
    __shared__ float s_C[64];
    __shared__ int s_pos[64];
    int tid = threadIdx.x;
    int e0 = blockIdx.x * 64;

    {   // stage rbf transposed
        int j = tid >> 2;
        int kk = (tid & 3) * 8;
        int e = e0 + j;
        float4 v0 = make_float4(0.f, 0.f, 0.f, 0.f), v1 = v0;
        if (e < E) {
            v0 = *(const float4*)(radial + (size_t)e * 32 + kk);
            v1 = *(const float4*)(radial + (size_t)e * 32 + kk + 4);
        }
        s_act[(kk + 0) * 68 + j] = v0.x;
        s_act[(kk + 1) * 68 + j] = v0.y;
        s_act[(kk + 2) * 68 + j] = v0.z;
        s_act[(kk + 3) * 68 + j] = v0.w;
        s_act[(kk + 4) * 68 + j] = v1.x;
        s_act[(kk + 5) * 68 + j] = v1.y;
        s_act[(kk + 6) * 68 + j] = v1.z;
        s_act[(kk + 7) * 68 + j] = v1.w;
    }
    if (tid < 64) {
        int e = e0 + tid;
        float d = (e < E) ? d_ij[e] : 1e9f;
        s_C[tid] = (d < 5.0f) ? 0.5f * (cosf((float)M_PI * d * 0.2f) + 1.0f) : 0.0f;
        s_pos[tid] = (e < E) ? posOf[e] : 0;
    }
    __syncthreads();

    int et = tid >> 4, ct = tid & 15;
    int e4 = et * 4;

#define FMA16(ACC, W4, A0, A1, A2, A3)                                  \
    ACC.x += W4.x * A0.x + W4.y * A1.x + W4.z * A2.x + W4.w * A3.x;     \
    ACC.y += W4.x * A0.y + W4.y * A1.y + W4.z * A2.y + W4.w * A3.y;     \
    ACC.z += W4.x * A0.z + W4.y * A1.z + W4.z * A2.z + W4.w * A3.z;     \
    ACC.w += W4.x * A0.w + W4.y * A1.w + W4.z * A2.w + W4.w * A3.w;

    // ---- layer 1: 32 -> 64
    {
        float4 acc1[4];
#pragma unroll
        for (int cc = 0; cc < 4; ++cc) {
            float b = b1[ct * 4 + cc];
            acc1[cc] = make_float4(b, b, b, b);
        }
        for (int k = 0; k < 32; k += 4) {
            float4 a0 = *(const float4*)&s_act[(k + 0) * 68 + e4];
            float4 a1 = *(const float4*)&s_act[(k + 1) * 68 + e4];
            float4 a2 = *(const float4*)&s_act[(k + 2) * 68 + e4];
            float4 a3 = *(const float4*)&s_act[(k + 3) * 68 + e4];
#pragma unroll
            for (int cc = 0; cc < 4; ++cc) {
                float4 w4 = *(const float4*)&W1[(ct * 4 + cc) * 32 + k];
                FMA16(acc1[cc], w4, a0, a1, a2, a3)
            }
        }
        __syncthreads();
#pragma unroll
        for (int cc = 0; cc < 4; ++cc) {
            int c = ct * 4 + cc;
            float4 v = make_float4(silu_f(acc1[cc].x), silu_f(acc1[cc].y),
                                   silu_f(acc1[cc].z), silu_f(acc1[cc].w));
            *(float4*)&s_act[c * 68 + e4] = v;
        }
        __syncthreads();
    }

    // ---- layer 2: 64 -> 128
    {
        float4 acc2[2][4];
#pragma unroll
        for (int co = 0; co < 2; ++co)
#pragma unroll
            for (int cc = 0; cc < 4; ++cc) {
                float b = b2[co * 64 + ct * 4 + cc];
                acc2[co][cc] = make_float4(b, b, b, b);
            }
        for (int k = 0; k < 64; k += 4) {
            float4 a0 = *(const float4*)&s_act[(k + 0) * 68 + e4];
            float4 a1 = *(const float4*)&s_act[(k + 1) * 68 + e4];
            float4 a2 = *(const float4*)&s_act[(k + 2) * 68 + e4];
            float4 a3 = *(const float4*)&s_act[(k + 3) * 68 + e4];
#pragma unroll
            for (int co = 0; co < 2; ++co)
#pragma unroll
                for (int cc = 0; cc < 4; ++cc) {
                    float4 w4 = *(const float4*)&W2[(co * 64 + ct * 4 + cc) * 64 + k];
                    FMA16(acc2[co][cc], w4, a0, a1, a2, a3)
                }
        }
        __syncthreads();
#pragma unroll
        for (int co = 0; co < 2; ++co)
#pragma unroll
            for (int cc = 0; cc < 4; ++cc) {
                int c = co * 64 + ct * 4 + cc;
                float4 v = make_float4(silu_f(acc2[co][cc].x), silu_f(acc2[co][cc].y),
                                       silu_f(acc2[co][cc].z), silu_f(acc2[co][cc].w));
                *(float4*)&s_act[c * 68 + e4] = v;
            }
        __syncthreads();
    }

    // ---- layer 3: 128 -> 192, output row c = cmp*64 + f
    {
        float4 acc3[3][4];
#pragma unroll
        for (int co = 0; co < 3; ++co)
#pragma unroll
            for (int cc = 0; cc < 4; ++cc) {
                float b = b3[(ct * 4 + cc) * 3 + co];
                acc3[co][cc] = make_float4(b, b, b, b);
            }
        for (int k = 0; k < 128; k += 4) {
            float4 a0 = *(const float4*)&s_act[(k + 0) * 68 + e4];
            float4 a1 = *(const float4*)&s_act[(k + 1) * 68 + e4];
            float4 a2 = *(const float4*)&s_act[(k + 2) * 68 + e4];
            float4 a3 = *(const float4*)&s_act[(k + 3) * 68 + e4];
#pragma unroll
            for (int co = 0; co < 3; ++co)
#pragma unroll
                for (int cc = 0; cc < 4; ++cc) {
                    float4 w4 = *(const float4*)&W3[((ct * 4 + cc) * 3 + co) * 128 + k];
                    FMA16(acc3[co][cc], w4, a0, a1, a2, a3)
                }
        }
        __syncthreads();
        float4 C4 = make_float4(s_C[e4], s_C[e4 + 1], s_C[e4 + 2], s_C[e4 + 3]);
#pragma unroll
        for (int co = 0; co < 3; ++co)
#pragma unroll
            for (int cc = 0; cc < 4; ++cc) {
                int c = co * 64 + ct * 4 + cc;
                float4 v = make_float4(silu_f(acc3[co][cc].x) * C4.x,
                                       silu_f(acc3[co][cc].y) * C4.y,
                                       silu_f(acc3[co][cc].z) * C4.z,
                                       silu_f(acc3[co][cc].w) * C4.w);
                *(float4*)&s_act[c * 68 + e4] = v;
            }
        __syncthreads();
    }
#undef FMA16

    // ---- write fp16 features to sorted row
    {
        int j = tid >> 2, q = tid & 3;
        int e = e0 + j;
        if (e < E) {
            int pos = s_pos[j];
            __half tmp[48] __attribute__((aligned(16)));
#pragma unroll
            for (int t = 0; t < 48; ++t)
                tmp[t] = __float2half(s_act[(q * 48 + t) * 68 + j]);
            float4* dst = (float4*)(rfvS + (size_t)pos * 192 + q * 48);
            const float4* src = (const float4*)tmp;
#pragma unroll
            for (int t = 0; t < 6; ++t) dst[t] = src[t];
        }
    }
}

// ---------------------------------------------------------------------------
// Gather + node-mix: one wave per node, lane = f. Accumulate messages in
// registers over the node's sorted edge range, then fuse the O(3) mix:
// M=recon(acc), Y=recon(T[n]), P=scale*(MY+YM), decompose+normalize -> U2.
// ---------------------------------------------------------------------------
__global__ __launch_bounds__(256) void k_gather_mix(
    const __half* __restrict__ rfvS, const int* __restrict__ off,
    const int* __restrict__ dstp, const float* __restrict__ T,
    const float* __restrict__ charges, float* __restrict__ U2, int N)
{
    int w = threadIdx.x >> 6, lane = threadIdx.x & 63;
    int n = blockIdx.x * 4 + w;
    if (n >= N) return;
    size_t slab = (size_t)N * 64;
    int p0 = off[n], p1 = off[n + 1];
    float acc[9];
#pragma unroll
    for (int c = 0; c < 9; ++c) acc[c] = 0.f;
    for (int p = p0; p < p1; ++p) {
        int d = dstp[p];
        const __half* r = rfvS + (size_t)p * 192;
        float rf0 = __half2float(r[lane]);
        float rf1 = __half2float(r[64 + lane]);
        float rf2 = __half2float(r[128 + lane]);
        size_t bd = (size_t)d * 64 + lane;
        acc[0] += rf0 * T[0 * slab + bd];
        acc[1] += rf1 * T[1 * slab + bd];
        acc[2] += rf1 * T[2 * slab + bd];
        acc[3] += rf1 * T[3 * slab + bd];
#pragma unroll
        for (int c = 4; c < 9; ++c) acc[c] += rf2 * T[c * slab + bd];
    }
    size_t t = (size_t)n * 64 + lane;
    float uy[9];
#pragma unroll
    for (int c = 0; c < 9; ++c) uy[c] = T[c * slab + t];
    float M[9], Y[9];
    recon(acc, M);
    recon(uy, Y);
    float P[9];
#pragma unroll
    for (int i = 0; i < 3; ++i)
#pragma unroll
        for (int j = 0; j < 3; ++j) {
            float s = 0.f;
#pragma unroll
            for (int k = 0; k < 3; ++k)
                s += M[i * 3 + k] * Y[k * 3 + j] + Y[i * 3 + k] * M[k * 3 + j];
            P[i * 3 + j] = s;
        }
    float sc = 1.0f + 0.1f * charges[n];
    float nrm = 0.f;
#pragma unroll
    for (int i = 0; i < 9; ++i) { P[i] *= sc; nrm += P[i] * P[i]; }
    float inv = 1.0f / (nrm + 1.0f);
    float lam = (P[0] + P[4] + P[8]) * (1.f / 3.f);
    U2[0 * slab + t] = lam * inv;
    U2[1 * slab + t] = 0.5f * (P[1] - P[3]) * inv;
    U2[2 * slab + t] = 0.5f * (P[2] - P[6]) * inv;
    U2[3 * slab + t] = 0.5f * (P[5] - P[7]) * inv;
    U2[4 * slab + t] = (P[0] - lam) * inv;
    U2[5 * slab + t] = 0.5f * (P[1] + P[3]) * inv;
    U2[6 * slab + t] = 0.5f * (P[2] + P[6]) * inv;
    U2[7 * slab + t] = (P[4] - lam) * inv;
    U2[8 * slab + t] = 0.5f * (P[5] + P[7]) * inv;
}

// ---------------------------------------------------------------------------
// Fallback (round-1): fused edge MLP + atomic scatter.
// ---------------------------------------------------------------------------
__global__ __launch_bounds__(256) void k_edge(
    const float* __restrict__ radial, const float* __restrict__ d_ij,
    const int* __restrict__ pair,
    const float* __restrict__ W1, const float* __restrict__ b1,
    const float* __restrict__ W2, const float* __restrict__ b2,
    const float* __restrict__ W3, const float* __restrict__ b3,
    const float* __restrict__ T, float* __restrict__ msg,
    int E, int N)
{
    __shared__ float s_act[192 * 68];
    __shared__ float s_C[64];
    __shared__ int s_src[64];
    __shared__ int s_dst[64];
    int tid = threadIdx.x;
    int e0 = blockIdx.x * 64;

    {
        int j = tid >> 2;
        int kk = (tid & 3) * 8;
        int e = e0 + j;
        float4 v0 = make_float4(0.f, 0.f, 0.f, 0.f), v1 = v0;
        if (e < E) {
            v0 = *(const float4*)(radial + (size_t)e * 32 + kk);
            v1 = *(const float4*)(radial + (size_t)e * 32 + kk + 4);
        }
        s_act[(kk + 0) * 68 + j] = v0.x;
        s_act[(kk + 1) * 68 + j] = v0.y;
        s_act[(kk + 2) * 68 + j] = v0.z;
        s_act[(kk + 3) * 68 + j] = v0.w;
        s_act[(kk + 4) * 68 + j] = v1.x;
        s_act[(kk + 5) * 68 + j] = v1.y;
        s_act[(kk + 6) * 68 + j] = v1.z;
        s_act[(kk + 7) * 68 + j] = v1.w;
    }
    if (tid < 64) {
        int e = e0 + tid;
        float d = (e < E) ? d_ij[e] : 1e9f;
        s_C[tid] = (d < 5.0f) ? 0.5f * (cosf((float)M_PI * d * 0.2f) + 1.0f) : 0.0f;
        s_src[tid] = (e < E) ? pair[e] : 0;
        s_dst[tid] = (e < E) ? pair[(size_t)E + e] : 0;
    }
    __syncthreads();

    int et = tid >> 4, ct = tid & 15;
    int e4 = et * 4;

#define FMA16(ACC, W4, A0, A1, A2, A3)                                  \
    ACC.x += W4.x * A0.x + W4.y * A1.x + W4.z * A2.x + W4.w * A3.x;     \
    ACC.y += W4.x * A0.y + W4.y * A1.y + W4.z * A2.y + W4.w * A3.y;     \
    ACC.z += W4.x * A0.z + W4.y * A1.z + W4.z * A2.z + W4.w * A3.z;     \
    ACC.w += W4.x * A0.w + W4.y * A1.w + W4.z * A2.w + W4.w * A3.w;

    {
        float4 acc1[4];
#pragma unroll
        for (int cc = 0; cc < 4; ++cc) {
            float b = b1[ct * 4 + cc];
            acc1[cc] = make_float4(b, b, b, b);
        }
        for (int k = 0; k < 32; k += 4) {
            float4 a0 = *(const float4*)&s_act[(k + 0) * 68 + e4];
            float4 a1 = *(const float4*)&s_act[(k + 1) * 68 + e4];
            float4 a2 = *(const float4*)&s_act[(k + 2) * 68 + e4];
            float4 a3 = *(const float4*)&s_act[(k + 3) * 68 + e4];
#pragma unroll
            for (int cc = 0; cc < 4; ++cc) {
                float4 w4 = *(const float4*)&W1[(ct * 4 + cc) * 32 + k];
                FMA16(acc1[cc], w4, a0, a1, a2, a3)
            }
        }
        __syncthreads();
#pragma unroll
        for (int cc = 0; cc < 4; ++cc) {
            int c = ct * 4 + cc;
            float4 v = make_float4(silu_f(acc1[cc].x), silu_f(acc1[cc].y),
                                   silu_f(acc1[cc].z), silu_f(acc1[cc].w));
            *(float4*)&s_act[c * 68 + e4] = v;
        }
        __syncthreads();
    }
    {
        float4 acc2[2][4];
#pragma unroll
        for (int co = 0; co < 2; ++co)
#pragma unroll
            for (int cc = 0; cc < 4; ++cc) {
                float b = b2[co * 64 + ct * 4 + cc];
                acc2[co][cc] = make_float4(b, b, b, b);
            }
        for (int k = 0; k < 64; k += 4) {
            float4 a0 = *(const float4*)&s_act[(k + 0) * 68 + e4];
            float4 a1 = *(const float4*)&s_act[(k + 1) * 68 + e4];
            float4 a2 = *(const float4*)&s_act[(k + 2) * 68 + e4];
            float4 a3 = *(const float4*)&s_act[(k + 3) * 68 + e4];
#pragma unroll
            for (int co = 0; co < 2; ++co)
#pragma unroll
                for (int cc = 0; cc < 4; ++cc) {
                    float4 w4 = *(const float4*)&W2[(co * 64 + ct * 4 + cc) * 64 + k];
                    FMA16(acc2[co][cc], w4, a0, a1, a2, a3)
                }
        }
        __syncthreads();
#pragma unroll
        for (int co = 0; co < 2; ++co)
#pragma unroll
            for (int cc = 0; cc < 4; ++cc) {
                int c = co * 64 + ct * 4 + cc;
                float4 v = make_float4(silu_f(acc2[co][cc].x), silu_f(acc2[co][cc].y),
                                       silu_f(acc2[co][cc].z), silu_f(acc2[co][cc].w));
                *(float4*)&s_act[c * 68 + e4] = v;
            }
        __syncthreads();
    }
    {
        float4 acc3[3][4];
#pragma unroll
        for (int co = 0; co < 3; ++co)
#pragma unroll
            for (int cc = 0; cc < 4; ++cc) {
                float b = b3[(ct * 4 + cc) * 3 + co];
                acc3[co][cc] = make_float4(b, b, b, b);
            }
        for (int k = 0; k < 128; k += 4) {
            float4 a0 = *(const float4*)&s_act[(k + 0) * 68 + e4];
            float4 a1 = *(const float4*)&s_act[(k + 1) * 68 + e4];
            float4 a2 = *(const float4*)&s_act[(k + 2) * 68 + e4];
            float4 a3 = *(const float4*)&s_act[(k + 3) * 68 + e4];
#pragma unroll
            for (int co = 0; co < 3; ++co)
#pragma unroll
                for (int cc = 0; cc < 4; ++cc) {
                    float4 w4 = *(const float4*)&W3[((ct * 4 + cc) * 3 + co) * 128 + k];
                    FMA16(acc3[co][cc], w4, a0, a1, a2, a3)
                }
        }
        __syncthreads();
        float4 C4 = make_float4(s_C[e4], s_C[e4 + 1], s_C[e4 + 2], s_C[e4 + 3]);
#pragma unroll
        for (int co = 0; co < 3; ++co)
#pragma unroll
            for (int cc = 0; cc < 4; ++cc) {
                int c = co * 64 + ct * 4 + cc;
                float4 v = make_float4(silu_f(acc3[co][cc].x) * C4.x,
                                       silu_f(acc3[co][cc].y) * C4.y,
                                       silu_f(acc3[co][cc].z) * C4.z,
                                       silu_f(acc3[co][cc].w) * C4.w);
                *(float4*)&s_act[c * 68 + e4] = v;
            }
        __syncthreads();
    }
#undef FMA16
    {
        int wv = tid >> 6, lane = tid & 63;
        size_t slab = (size_t)N * 64;
        for (int e = wv * 16; e < wv * 16 + 16; ++e) {
            if (e0 + e >= E) break;
            int s = s_src[e], d = s_dst[e];
            float rf0 = s_act[(0 * 64 + lane) * 68 + e];
            float rf1 = s_act[(1 * 64 + lane) * 68 + e];
            float rf2 = s_act[(2 * 64 + lane) * 68 + e];
            size_t bd = (size_t)d * 64 + lane;
            size_t bs = (size_t)s * 64 + lane;
            atomicAdd(&msg[0 * slab + bs], rf0 * T[0 * slab + bd]);
            atomicAdd(&msg[1 * slab + bs], rf1 * T[1 * slab + bd]);
            atomicAdd(&msg[2 * slab + bs], rf1 * T[2 * slab + bd]);
            atomicAdd(&msg[3 * slab + bs], rf1 * T[3 * slab + bd]);
#pragma unroll
            for (int c = 4; c < 9; ++c)
                atomicAdd(&msg[c * slab + bs], rf2 * T[c * slab + bd]);
        }
    }
}

__global__ __launch_bounds__(256) void k_node_mix(
    const float* __restrict__ msg, const float* __restrict__ T,
    const float* __restrict__ charges, float* __restrict__ U2, int N)
{
    int t = blockIdx.x * 256 + threadIdx.x;
    if (t >= N * 64) return;
    int n = t >> 6;
    size_t slab = (size_t)N * 64;
    float um[9], uy[9];
#pragma unroll
    for (int c = 0; c < 9; ++c) { um[c] = msg[c * slab + t]; uy[c] = T[c * slab + t]; }
    float M[9], Y[9];
    recon(um, M);
    recon(uy, Y);
    float P[9];
#pragma unroll
    for (int i = 0; i < 3; ++i)
#pragma unroll
        for (int j = 0; j < 3; ++j) {
            float s = 0.f;
#pragma unroll
            for (int k = 0; k < 3; ++k)
                s += M[i * 3 + k] * Y[k * 3 + j] + Y[i * 3 + k] * M[k * 3 + j];
            P[i * 3 + j] = s;
        }
    float sc = 1.0f + 0.1f * charges[n];
    float nrm = 0.f;
#pragma unroll
    for (int i = 0; i < 9; ++i) { P[i] *= sc; nrm += P[i] * P[i]; }
    float inv = 1.0f / (nrm + 1.0f);
    float lam = (P[0] + P[4] + P[8]) * (1.f / 3.f);
    U2[0 * slab + t] = lam * inv;
    U2[1 * slab + t] = 0.5f * (P[1] - P[3]) * inv;
    U2[2 * slab + t] = 0.5f * (P[2] - P[6]) * inv;
    U2[3 * slab + t] = 0.5f * (P[5] - P[7]) * inv;
    U2[4 * slab + t] = (P[0] - lam) * inv;
    U2[5 * slab + t] = 0.5f * (P[1] + P[3]) * inv;
    U2[6 * slab + t] = 0.5f * (P[2] + P[6]) * inv;
    U2[7 * slab + t] = (P[4] - lam) * inv;
    U2[8 * slab + t] = 0.5f * (P[5] + P[7]) * inv;
}

// ---------------------------------------------------------------------------
// Output: out = Xn + dX + scale * dX@dX
// ---------------------------------------------------------------------------
__global__ __launch_bounds__(256) void k_out(
    const float* __restrict__ V, const float* __restrict__ X,
    const float* __restrict__ charges, float* __restrict__ out, int N)
{
    __shared__ float s_x[2304];
    __shared__ float s_o[2304];
    int tid = threadIdx.x;
    int blk = blockIdx.x;
    size_t base = (size_t)blk * 2304;
    size_t total = (size_t)N * 576;
    for (int idx = tid; idx < 2304; idx += 256) {
        size_t gi = base + idx;
        s_x[idx] = (gi < total) ? X[gi] : 0.f;
    }
    __syncthreads();
    int t = blk * 256 + tid;
    if (t < N * 64) {
        int n = t >> 6;
        int w = tid >> 6, f = tid & 63;
        size_t slab = (size_t)N * 64;
        float m[9]; float n2 = 0.f;
#pragma unroll
        for (int i = 0; i < 9; ++i) { m[i] = s_x[w * 576 + f * 9 + i]; n2 += m[i] * m[i]; }
        float invn = 1.0f / (n2 + 1.0f);
#pragma unroll
        for (int i = 0; i < 9; ++i) m[i] *= invn;
        float uv[9];
#pragma unroll
        for (int c = 0; c < 9; ++c) uv[c] = V[c * slab + t];
        float dX[9];
        recon(uv, dX);
        float sc = 1.0f + 0.1f * charges[n];
#pragma unroll
        for (int i = 0; i < 3; ++i)
#pragma unroll
            for (int j = 0; j < 3; ++j) {
                float s = 0.f;
#pragma unroll
                for (int k = 0; k < 3; ++k) s += dX[i * 3 + k] * dX[k * 3 + j];
                s_o[w * 576 + f * 9 + i * 3 + j] = m[i * 3 + j] + dX[i * 3 + j] + sc * s;
            }
    }
    __syncthreads();
    for (int idx = tid; idx < 2304; idx += 256) {
        size_t gi = base + idx;
        if (gi < total) out[gi] = s_o[idx];
    }
}

// ---------------------------------------------------------------------------
extern "C" void kernel_launch(void* const* d_in, const int* in_sizes, int n_in,
                              void* d_out, int out_size, void* d_ws, size_t ws_size,
                              hipStream_t stream)
{
    const float* X       = (const float*)d_in[0];
    const int*   pair    = (const int*)d_in[1];
    const float* dij     = (const float*)d_in[2];
    const float* radial  = (const float*)d_in[3];
    const float* charges = (const float*)d_in[4];
    const float* W1  = (const float*)d_in[5];
    const float* b1  = (const float*)d_in[6];
    const float* W2  = (const float*)d_in[7];
    const float* b2  = (const float*)d_in[8];
    const float* W3  = (const float*)d_in[9];
    const float* b3  = (const float*)d_in[10];
    const float* Wl0 = (const float*)d_in[11];
    const float* Wl1 = (const float*)d_in[12];
    const float* Wl2 = (const float*)d_in[13];
    const float* Wl3 = (const float*)d_in[14];
    const float* Wl4 = (const float*)d_in[15];
    const float* Wl5 = (const float*)d_in[16];

    int N = in_sizes[4];
    int E = in_sizes[2];
    int R = 9 * N;
    int nb_gemm = (R + 63) / 64;
    int nb_node4 = (N + 3) / 4;
    int nb_edge = (E + 63) / 64;
    size_t slab9 = (size_t)N * 64 * 9;

    // new-path workspace requirement
    size_t halfFloats = (size_t)E * 96;              // E*192 halfs as floats
    size_t intCount = (size_t)N * 3 + 1 + (size_t)E * 2;
    size_t needed = (2 * slab9 + halfFloats) * sizeof(float) + intCount * sizeof(int);

    if (ws_size >= needed) {
        float* U    = (float*)d_ws;
        float* T    = U + slab9;
        __half* rfvS = (__half*)(T + slab9);
        int* ints   = (int*)((float*)rfvS + halfFloats);
        int* count  = ints;
        int* off    = count + N;
        int* cursor = off + N + 1;
        int* posOf  = cursor + N;
        int* dstp   = posOf + E;
        float* V    = (float*)rfvS;   // reuse after gather

        hipMemsetAsync(count, 0, (size_t)N * sizeof(int), stream);

        k_node_prep<<<nb_node4, 256, 0, stream>>>(X, U, N);
        k_comp_gemm<<<nb_gemm, 256, 0, stream>>>(U, T, Wl0, Wl1, Wl2, R, N);

        k_hist<<<(E + 255) / 256, 256, 0, stream>>>(pair, count, E);
        k_scan<<<1, 1024, 0, stream>>>(count, off, cursor, N, E);
        k_scatter_sort<<<(E + 255) / 256, 256, 0, stream>>>(pair, cursor, posOf, dstp, E);

        k_edge_mlp<<<nb_edge, 256, 0, stream>>>(radial, dij, posOf,
                                                W1, b1, W2, b2, W3, b3, rfvS, E);

        float* U2 = U;
        k_gather_mix<<<nb_node4, 256, 0, stream>>>(rfvS, off, dstp, T, charges, U2, N);

        k_comp_gemm<<<nb_gemm, 256, 0, stream>>>(U2, V, Wl3, Wl4, Wl5, R, N);
        k_out<<<(N * 64 + 255) / 256, 256, 0, stream>>>(V, X, charges, (float*)d_out, N);
    } else {
        // fallback: round-1 atomic path
        float* U   = (float*)d_ws;
        float* T   = U + slab9;
        float* msg = T + slab9;

        hipMemsetAsync(msg, 0, slab9 * sizeof(float), stream);
        k_node_prep<<<nb_node4, 256, 0, stream>>>(X, U, N);
        k_comp_gemm<<<nb_gemm, 256, 0, stream>>>(U, T, Wl0, Wl1, Wl2, R, N);
        k_edge<<<nb_edge, 256, 0, stream>>>(radial, dij, pair,
                                            W1, b1, W2, b2, W3, b3, T, msg, E, N);
        float* U2 = U;
        k_node_mix<<<(N * 64 + 255) / 256, 256, 0, stream>>>(msg, T, charges, U2, N);
        float* Vv = msg;
        k_comp_gemm<<<nb_gemm, 256, 0, stream>>>(U2, Vv, Wl3, Wl4, Wl5, R, N);
        k_out<<<(N * 64 + 255) / 256, 256, 0, stream>>>(Vv, X, charges, (float*)d_out, N);
    }
}

// Round 3
// 2137.844 us; speedup vs baseline: 1.1253x; 1.1253x over previous
//
#include <hip/hip_runtime.h>
#include <math.h>

#ifndef M_PI
#define M_PI 3.14159265358979323846
#endif

// ---------------------------------------------------------------------------
// TensorNet interaction, fp32.
// Compressed irreducible rep per (n,f): u[9] =
//   { lam, a01, a02, a12, s00, s01, s02, s11, s12 }   (s22 = -s00-s11)
// Slab layout for node tensors: [9][N][F] (F contiguous).
//
// Workspace (needs ~120.3 MB, proven available since rounds 1-2 used 172.8):
//   slab A (57.6 MB): U -> (in-place GEMM) -> T
//   slab B (57.6 MB): msg -> (in-place mix) -> U2 -> (in-place GEMM) -> V
//   ints  (~5.1 MB): count[N], off[N+1], cursor[N], eOf[E], dstp[E], srcp[E]
//
// Message pass: edges CSR-sorted by src; each block = 64 consecutive sorted
// positions; waves accumulate per-node runs in registers and flush with a
// plain store (node range interior to block) or atomicAdd (boundary runs).
// ~7M lane-atomics vs round-1's 230M.
// ---------------------------------------------------------------------------

__device__ __forceinline__ float silu_f(float x) {
    return x / (1.0f + __expf(-x));
}

__device__ __forceinline__ void recon(const float u[9], float M[9]) {
    M[0] =  u[0] + u[4];
    M[1] =  u[1] + u[5];
    M[2] =  u[2] + u[6];
    M[3] = -u[1] + u[5];
    M[4] =  u[0] + u[7];
    M[5] =  u[3] + u[8];
    M[6] = -u[2] + u[6];
    M[7] = -u[3] + u[8];
    M[8] =  u[0] - u[4] - u[7];
}

// ---------------------------------------------------------------------------
// K1: per (n,f): Xn = X/(|X|^2+1), decompose -> U slabs [9][N][64]
// ---------------------------------------------------------------------------
__global__ __launch_bounds__(256) void k_node_prep(
    const float* __restrict__ X, float* __restrict__ U, int N)
{
    __shared__ float s_x[2304];
    int tid = threadIdx.x;
    size_t base = (size_t)blockIdx.x * 2304;
    size_t total = (size_t)N * 576;
    for (int idx = tid; idx < 2304; idx += 256) {
        size_t gi = base + idx;
        s_x[idx] = (gi < total) ? X[gi] : 0.f;
    }
    __syncthreads();
    int w = tid >> 6, f = tid & 63;
    int n = blockIdx.x * 4 + w;
    if (n >= N) return;
    float m[9]; float n2 = 0.f;
#pragma unroll
    for (int i = 0; i < 9; ++i) { m[i] = s_x[w * 576 + f * 9 + i]; n2 += m[i] * m[i]; }
    float inv = 1.0f / (n2 + 1.0f);
#pragma unroll
    for (int i = 0; i < 9; ++i) m[i] *= inv;
    float lam = (m[0] + m[4] + m[8]) * (1.f / 3.f);
    size_t slab = (size_t)N * 64;
    size_t t = (size_t)n * 64 + f;
    U[0 * slab + t] = lam;
    U[1 * slab + t] = 0.5f * (m[1] - m[3]);
    U[2 * slab + t] = 0.5f * (m[2] - m[6]);
    U[3 * slab + t] = 0.5f * (m[5] - m[7]);
    U[4 * slab + t] = m[0] - lam;
    U[5 * slab + t] = 0.5f * (m[1] + m[3]);
    U[6 * slab + t] = 0.5f * (m[2] + m[6]);
    U[7 * slab + t] = m[4] - lam;
    U[8 * slab + t] = 0.5f * (m[5] + m[7]);
}

// ---------------------------------------------------------------------------
// Comp GEMM (in-place safe: block reads only its own 64 rows into LDS before
// writing them back). out[row][g] = sum_f in[row][f]*Wsel[g][f], row = c*N+n.
// ---------------------------------------------------------------------------
__global__ __launch_bounds__(256) void k_comp_gemm(
    const float* in, float* out,
    const float* __restrict__ Wa, const float* __restrict__ Wb,
    const float* __restrict__ Wc, int R, int N)
{
    __shared__ float s_a[64 * 68];
    int tid = threadIdx.x;
    int r0 = blockIdx.x * 64;
    for (int idx = tid; idx < 1024; idx += 256) {
        int row = idx >> 4;
        int k4 = (idx & 15) << 2;
        int gr = r0 + row;
        float4 v = make_float4(0.f, 0.f, 0.f, 0.f);
        if (gr < R) v = *(const float4*)(in + (size_t)gr * 64 + k4);
        s_a[(k4 + 0) * 68 + row] = v.x;
        s_a[(k4 + 1) * 68 + row] = v.y;
        s_a[(k4 + 2) * 68 + row] = v.z;
        s_a[(k4 + 3) * 68 + row] = v.w;
    }
    __syncthreads();
    int et = tid >> 4, ct = tid & 15;
    int c0 = ct * 4;
    int rbase = r0 + et * 4;
    float4 acc[4];
#pragma unroll
    for (int cc = 0; cc < 4; ++cc) acc[cc] = make_float4(0.f, 0.f, 0.f, 0.f);

    int cA = r0 / N;
    int rlast = min(r0 + 63, R - 1);
    int cB = rlast / N;
    int gA = (cA == 0) ? 0 : (cA < 4 ? 1 : 2);
    int gB = (cB == 0) ? 0 : (cB < 4 ? 1 : 2);

    if (gA == gB) {
        const float* W = (gA == 0) ? Wa : (gA == 1 ? Wb : Wc);
        for (int k = 0; k < 64; k += 4) {
            float4 a0 = *(const float4*)&s_a[(k + 0) * 68 + et * 4];
            float4 a1 = *(const float4*)&s_a[(k + 1) * 68 + et * 4];
            float4 a2 = *(const float4*)&s_a[(k + 2) * 68 + et * 4];
            float4 a3 = *(const float4*)&s_a[(k + 3) * 68 + et * 4];
#pragma unroll
            for (int cc = 0; cc < 4; ++cc) {
                float4 w4 = *(const float4*)&W[(c0 + cc) * 64 + k];
                acc[cc].x += w4.x * a0.x + w4.y * a1.x + w4.z * a2.x + w4.w * a3.x;
                acc[cc].y += w4.x * a0.y + w4.y * a1.y + w4.z * a2.y + w4.w * a3.y;
                acc[cc].z += w4.x * a0.z + w4.y * a1.z + w4.z * a2.z + w4.w * a3.z;
                acc[cc].w += w4.x * a0.w + w4.y * a1.w + w4.z * a2.w + w4.w * a3.w;
            }
        }
    } else {
        const float* Wi[4];
#pragma unroll
        for (int i = 0; i < 4; ++i) {
            int r = min(rbase + i, R - 1);
            int c = r / N;
            int g = (c == 0) ? 0 : (c < 4 ? 1 : 2);
            Wi[i] = (g == 0) ? Wa : (g == 1 ? Wb : Wc);
        }
        for (int k = 0; k < 64; ++k) {
            float a0 = s_a[k * 68 + et * 4 + 0];
            float a1 = s_a[k * 68 + et * 4 + 1];
            float a2 = s_a[k * 68 + et * 4 + 2];
            float a3 = s_a[k * 68 + et * 4 + 3];
#pragma unroll
            for (int cc = 0; cc < 4; ++cc) {
                acc[cc].x += Wi[0][(c0 + cc) * 64 + k] * a0;
                acc[cc].y += Wi[1][(c0 + cc) * 64 + k] * a1;
                acc[cc].z += Wi[2][(c0 + cc) * 64 + k] * a2;
                acc[cc].w += Wi[3][(c0 + cc) * 64 + k] * a3;
            }
        }
    }
    if (rbase + 0 < R) {
        float4 o = make_float4(acc[0].x, acc[1].x, acc[2].x, acc[3].x);
        *(float4*)(out + (size_t)(rbase + 0) * 64 + c0) = o;
    }
    if (rbase + 1 < R) {
        float4 o = make_float4(acc[0].y, acc[1].y, acc[2].y, acc[3].y);
        *(float4*)(out + (size_t)(rbase + 1) * 64 + c0) = o;
    }
    if (rbase + 2 < R) {
        float4 o = make_float4(acc[0].z, acc[1].z, acc[2].z, acc[3].z);
        *(float4*)(out + (size_t)(rbase + 2) * 64 + c0) = o;
    }
    if (rbase + 3 < R) {
        float4 o = make_float4(acc[0].w, acc[1].w, acc[2].w, acc[3].w);
        *(float4*)(out + (size_t)(rbase + 3) * 64 + c0) = o;
    }
}

// ---------------------------------------------------------------------------
// CSR sort of edges by src: histogram -> scan -> ranked placement.
// ---------------------------------------------------------------------------
__global__ __launch_bounds__(256) void k_hist(
    const int* __restrict__ pair, int* __restrict__ count, int E)
{
    int e = blockIdx.x * 256 + threadIdx.x;
    if (e < E) atomicAdd(&count[pair[e]], 1);
}

__global__ __launch_bounds__(1024) void k_scan(
    const int* __restrict__ count, int* __restrict__ off,
    int* __restrict__ cursor, int N, int E)
{
    __shared__ int s[1024];
    __shared__ int s_carry;
    int tid = threadIdx.x;
    if (tid == 0) s_carry = 0;
    __syncthreads();
    for (int base = 0; base < N; base += 1024) {
        int i = base + tid;
        int v = (i < N) ? count[i] : 0;
        s[tid] = v;
        __syncthreads();
        for (int d = 1; d < 1024; d <<= 1) {
            int t = (tid >= d) ? s[tid - d] : 0;
            __syncthreads();
            s[tid] += t;
            __syncthreads();
        }
        int incl = s[tid];
        int excl = s_carry + incl - v;
        if (i < N) { off[i] = excl; cursor[i] = excl; }
        __syncthreads();
        if (tid == 1023) s_carry += s[1023];
        __syncthreads();
    }
    if (tid == 0) off[N] = E;
}

__global__ __launch_bounds__(256) void k_scatter_sort(
    const int* __restrict__ pair, int* __restrict__ cursor,
    int* __restrict__ eOf, int* __restrict__ dstp, int* __restrict__ srcp, int E)
{
    int e = blockIdx.x * 256 + threadIdx.x;
    if (e < E) {
        int s = pair[e];
        int d = pair[(size_t)E + e];
        int pos = atomicAdd(&cursor[s], 1);
        eOf[pos] = e;
        dstp[pos] = d;
        srcp[pos] = s;
    }
}

// ---------------------------------------------------------------------------
// K2: fused edge MLP (32->64->128->192, SiLU, x cutoff) over SORTED edge
// positions + run-accumulated message pass (registers, store/atomic flush).
// Block = 64 sorted positions, 256 threads, activations in LDS [c][68].
// Message phase: wave wv owns comps {0,1}/{2,3}/{4,5,6}/{7,8}, lane = f.
// ---------------------------------------------------------------------------
__global__ __launch_bounds__(256) void k_edge_sorted(
    const float* __restrict__ radial, const float* __restrict__ d_ij,
    const int* __restrict__ eOf, const int* __restrict__ dstp,
    const int* __restrict__ srcp,
    const float* __restrict__ W1, const float* __restrict__ b1,
    const float* __restrict__ W2, const float* __restrict__ b2,
    const float* __restrict__ W3, const float* __restrict__ b3,
    const float* __restrict__ T, float* __restrict__ msg,
    int E, int N)
{
    __shared__ float s_act[192 * 68];
    __shared__ float s_C[64];
    __shared__ int s_e[64];
    __shared__ int s_src[64];
    __shared__ int s_dst[64];
    int tid = threadIdx.x;
    int p0 = blockIdx.x * 64;

    if (tid < 64) {
        int p = p0 + tid;
        int e = -1, s = 0, d = 0; float C = 0.f;
        if (p < E) {
            e = eOf[p];
            s = srcp[p];
            d = dstp[p];
            float dd = d_ij[e];
            C = (dd < 5.0f) ? 0.5f * (cosf((float)M_PI * dd * 0.2f) + 1.0f) : 0.0f;
        }
        s_e[tid] = e; s_src[tid] = s; s_dst[tid] = d; s_C[tid] = C;
    }
    __syncthreads();

    {   // stage rbf transposed: s_act[k][j] = radial[eOf[p0+j]*32+k]
        int j = tid >> 2;
        int kk = (tid & 3) * 8;
        int e = s_e[j];
        float4 v0 = make_float4(0.f, 0.f, 0.f, 0.f), v1 = v0;
        if (e >= 0) {
            v0 = *(const float4*)(radial + (size_t)e * 32 + kk);
            v1 = *(const float4*)(radial + (size_t)e * 32 + kk + 4);
        }
        s_act[(kk + 0) * 68 + j] = v0.x;
        s_act[(kk + 1) * 68 + j] = v0.y;
        s_act[(kk + 2) * 68 + j] = v0.z;
        s_act[(kk + 3) * 68 + j] = v0.w;
        s_act[(kk + 4) * 68 + j] = v1.x;
        s_act[(kk + 5) * 68 + j] = v1.y;
        s_act[(kk + 6) * 68 + j] = v1.z;
        s_act[(kk + 7) * 68 + j] = v1.w;
    }
    __syncthreads();

    int et = tid >> 4, ct = tid & 15;
    int e4 = et * 4;

#define FMA16(ACC, W4, A0, A1, A2, A3)                                  \
    ACC.x += W4.x * A0.x + W4.y * A1.x + W4.z * A2.x + W4.w * A3.x;     \
    ACC.y += W4.x * A0.y + W4.y * A1.y + W4.z * A2.y + W4.w * A3.y;     \
    ACC.z += W4.x * A0.z + W4.y * A1.z + W4.z * A2.z + W4.w * A3.z;     \
    ACC.w += W4.x * A0.w + W4.y * A1.w + W4.z * A2.w + W4.w * A3.w;

    // ---- layer 1: 32 -> 64
    {
        float4 acc1[4];
#pragma unroll
        for (int cc = 0; cc < 4; ++cc) {
            float b = b1[ct * 4 + cc];
            acc1[cc] = make_float4(b, b, b, b);
        }
        for (int k = 0; k < 32; k += 4) {
            float4 a0 = *(const float4*)&s_act[(k + 0) * 68 + e4];
            float4 a1 = *(const float4*)&s_act[(k + 1) * 68 + e4];
            float4 a2 = *(const float4*)&s_act[(k + 2) * 68 + e4];
            float4 a3 = *(const float4*)&s_act[(k + 3) * 68 + e4];
#pragma unroll
            for (int cc = 0; cc < 4; ++cc) {
                float4 w4 = *(const float4*)&W1[(ct * 4 + cc) * 32 + k];
                FMA16(acc1[cc], w4, a0, a1, a2, a3)
            }
        }
        __syncthreads();
#pragma unroll
        for (int cc = 0; cc < 4; ++cc) {
            int c = ct * 4 + cc;
            float4 v = make_float4(silu_f(acc1[cc].x), silu_f(acc1[cc].y),
                                   silu_f(acc1[cc].z), silu_f(acc1[cc].w));
            *(float4*)&s_act[c * 68 + e4] = v;
        }
        __syncthreads();
    }

    // ---- layer 2: 64 -> 128
    {
        float4 acc2[2][4];
#pragma unroll
        for (int co = 0; co < 2; ++co)
#pragma unroll
            for (int cc = 0; cc < 4; ++cc) {
                float b = b2[co * 64 + ct * 4 + cc];
                acc2[co][cc] = make_float4(b, b, b, b);
            }
        for (int k = 0; k < 64; k += 4) {
            float4 a0 = *(const float4*)&s_act[(k + 0) * 68 + e4];
            float4 a1 = *(const float4*)&s_act[(k + 1) * 68 + e4];
            float4 a2 = *(const float4*)&s_act[(k + 2) * 68 + e4];
            float4 a3 = *(const float4*)&s_act[(k + 3) * 68 + e4];
#pragma unroll
            for (int co = 0; co < 2; ++co)
#pragma unroll
                for (int cc = 0; cc < 4; ++cc) {
                    float4 w4 = *(const float4*)&W2[(co * 64 + ct * 4 + cc) * 64 + k];
                    FMA16(acc2[co][cc], w4, a0, a1, a2, a3)
                }
        }
        __syncthreads();
#pragma unroll
        for (int co = 0; co < 2; ++co)
#pragma unroll
            for (int cc = 0; cc < 4; ++cc) {
                int c = co * 64 + ct * 4 + cc;
                float4 v = make_float4(silu_f(acc2[co][cc].x), silu_f(acc2[co][cc].y),
                                       silu_f(acc2[co][cc].z), silu_f(acc2[co][cc].w));
                *(float4*)&s_act[c * 68 + e4] = v;
            }
        __syncthreads();
    }

    // ---- layer 3: 128 -> 192, output row c = cmp*64 + f
    {
        float4 acc3[3][4];
#pragma unroll
        for (int co = 0; co < 3; ++co)
#pragma unroll
            for (int cc = 0; cc < 4; ++cc) {
                float b = b3[(ct * 4 + cc) * 3 + co];
                acc3[co][cc] = make_float4(b, b, b, b);
            }
        for (int k = 0; k < 128; k += 4) {
            float4 a0 = *(const float4*)&s_act[(k + 0) * 68 + e4];
            float4 a1 = *(const float4*)&s_act[(k + 1) * 68 + e4];
            float4 a2 = *(const float4*)&s_act[(k + 2) * 68 + e4];
            float4 a3 = *(const float4*)&s_act[(k + 3) * 68 + e4];
#pragma unroll
            for (int co = 0; co < 3; ++co)
#pragma unroll
                for (int cc = 0; cc < 4; ++cc) {
                    float4 w4 = *(const float4*)&W3[((ct * 4 + cc) * 3 + co) * 128 + k];
                    FMA16(acc3[co][cc], w4, a0, a1, a2, a3)
                }
        }
        __syncthreads();
        float4 C4 = make_float4(s_C[e4], s_C[e4 + 1], s_C[e4 + 2], s_C[e4 + 3]);
#pragma unroll
        for (int co = 0; co < 3; ++co)
#pragma unroll
            for (int cc = 0; cc < 4; ++cc) {
                int c = co * 64 + ct * 4 + cc;
                float4 v = make_float4(silu_f(acc3[co][cc].x) * C4.x,
                                       silu_f(acc3[co][cc].y) * C4.y,
                                       silu_f(acc3[co][cc].z) * C4.z,
                                       silu_f(acc3[co][cc].w) * C4.w);
                *(float4*)&s_act[c * 68 + e4] = v;
            }
        __syncthreads();
    }
#undef FMA16

    // ---- message pass over sorted runs. wave wv -> comps, lane = f.
    {
        int wv = tid >> 6, lane = tid & 63;
        size_t slab = (size_t)N * 64;
        int cb = (wv < 3) ? wv * 2 : 7;        // comp base: 0,2,4,7
        int nc = (wv == 2) ? 3 : 2;            // comps per wave
        int c0 = cb, c1 = cb + 1, c2 = cb + 2; // c2 only if nc==3
        int gA = (c0 == 0) ? 0 : ((c0 < 4) ? 1 : 2);
        int gB = (c1 < 4) ? 1 : 2;
        const int rowA = (gA * 64 + lane) * 68;
        const int rowB = (gB * 64 + lane) * 68;
        const int rowC = (2 * 64 + lane) * 68;

        float acc0 = 0.f, acc1 = 0.f, acc2 = 0.f;
        int cur = -1, jstart = 0;
        int jmax = min(64, E - p0);

        auto flush = [&](int jend) {
            if (cur < 0) return;
            long ps = (long)p0 + jstart;
            long pe = (long)p0 + jend;
            bool lb = (ps == 0) || (srcp[ps - 1] != cur);
            bool rb = (pe >= (long)E) || (srcp[pe] != cur);
            size_t b = (size_t)cur * 64 + lane;
            if (lb && rb) {
                msg[(size_t)c0 * slab + b] = acc0;
                msg[(size_t)c1 * slab + b] = acc1;
                if (nc == 3) msg[(size_t)c2 * slab + b] = acc2;
            } else {
                atomicAdd(&msg[(size_t)c0 * slab + b], acc0);
                atomicAdd(&msg[(size_t)c1 * slab + b], acc1);
                if (nc == 3) atomicAdd(&msg[(size_t)c2 * slab + b], acc2);
            }
            acc0 = acc1 = acc2 = 0.f;
        };

        for (int j = 0; j < jmax; ++j) {
            int s = s_src[j];
            if (s != cur) { flush(j); cur = s; jstart = j; }
            int d = s_dst[j];
            size_t bd = (size_t)d * 64 + lane;
            acc0 += s_act[rowA + j] * T[(size_t)c0 * slab + bd];
            acc1 += s_act[rowB + j] * T[(size_t)c1 * slab + bd];
            if (nc == 3) acc2 += s_act[rowC + j] * T[(size_t)c2 * slab + bd];
        }
        flush(jmax);
    }
}

// ---------------------------------------------------------------------------
// K4a (in-place safe: msg/U2 may alias; per-thread read-all-then-write-all):
// M=recon(msg), Y=recon(T), P=scale*(MY+YM), decompose+normalize -> U2
// ---------------------------------------------------------------------------
__global__ __launch_bounds__(256) void k_node_mix(
    const float* msg, const float* __restrict__ T,
    const float* __restrict__ charges, float* U2, int N)
{
    int t = blockIdx.x * 256 + threadIdx.x;
    if (t >= N * 64) return;
    int n = t >> 6;
    size_t slab = (size_t)N * 64;
    float um[9], uy[9];
#pragma unroll
    for (int c = 0; c < 9; ++c) { um[c] = msg[c * slab + t]; uy[c] = T[c * slab + t]; }
    float M[9], Y[9];
    recon(um, M);
    recon(uy, Y);
    float P[9];
#pragma unroll
    for (int i = 0; i < 3; ++i)
#pragma unroll
        for (int j = 0; j < 3; ++j) {
            float s = 0.f;
#pragma unroll
            for (int k = 0; k < 3; ++k)
                s += M[i * 3 + k] * Y[k * 3 + j] + Y[i * 3 + k] * M[k * 3 + j];
            P[i * 3 + j] = s;
        }
    float sc = 1.0f + 0.1f * charges[n];
    float nrm = 0.f;
#pragma unroll
    for (int i = 0; i < 9; ++i) { P[i] *= sc; nrm += P[i] * P[i]; }
    float inv = 1.0f / (nrm + 1.0f);
    float lam = (P[0] + P[4] + P[8]) * (1.f / 3.f);
    U2[0 * slab + t] = lam * inv;
    U2[1 * slab + t] = 0.5f * (P[1] - P[3]) * inv;
    U2[2 * slab + t] = 0.5f * (P[2] - P[6]) * inv;
    U2[3 * slab + t] = 0.5f * (P[5] - P[7]) * inv;
    U2[4 * slab + t] = (P[0] - lam) * inv;
    U2[5 * slab + t] = 0.5f * (P[1] + P[3]) * inv;
    U2[6 * slab + t] = 0.5f * (P[2] + P[6]) * inv;
    U2[7 * slab + t] = (P[4] - lam) * inv;
    U2[8 * slab + t] = 0.5f * (P[5] + P[7]) * inv;
}

// ---------------------------------------------------------------------------
// Output: out = Xn + dX + scale * dX@dX   (Xn recomputed; dX = recon(V))
// ---------------------------------------------------------------------------
__global__ __launch_bounds__(256) void k_out(
    const float* __restrict__ V, const float* __restrict__ X,
    const float* __restrict__ charges, float* __restrict__ out, int N)
{
    __shared__ float s_x[2304];
    __shared__ float s_o[2304];
    int tid = threadIdx.x;
    int blk = blockIdx.x;
    size_t base = (size_t)blk * 2304;
    size_t total = (size_t)N * 576;
    for (int idx = tid; idx < 2304; idx += 256) {
        size_t gi = base + idx;
        s_x[idx] = (gi < total) ? X[gi] : 0.f;
    }
    __syncthreads();
    int t = blk * 256 + tid;
    if (t < N * 64) {
        int n = t >> 6;
        int w = tid >> 6, f = tid & 63;
        size_t slab = (size_t)N * 64;
        float m[9]; float n2 = 0.f;
#pragma unroll
        for (int i = 0; i < 9; ++i) { m[i] = s_x[w * 576 + f * 9 + i]; n2 += m[i] * m[i]; }
        float invn = 1.0f / (n2 + 1.0f);
#pragma unroll
        for (int i = 0; i < 9; ++i) m[i] *= invn;
        float uv[9];
#pragma unroll
        for (int c = 0; c < 9; ++c) uv[c] = V[c * slab + t];
        float dX[9];
        recon(uv, dX);
        float sc = 1.0f + 0.1f * charges[n];
#pragma unroll
        for (int i = 0; i < 3; ++i)
#pragma unroll
            for (int j = 0; j < 3; ++j) {
                float s = 0.f;
#pragma unroll
                for (int k = 0; k < 3; ++k) s += dX[i * 3 + k] * dX[k * 3 + j];
                s_o[w * 576 + f * 9 + i * 3 + j] = m[i * 3 + j] + dX[i * 3 + j] + sc * s;
            }
    }
    __syncthreads();
    for (int idx = tid; idx < 2304; idx += 256) {
        size_t gi = base + idx;
        if (gi < total) out[gi] = s_o[idx];
    }
}

// ---------------------------------------------------------------------------
extern "C" void kernel_launch(void* const* d_in, const int* in_sizes, int n_in,
                              void* d_out, int out_size, void* d_ws, size_t ws_size,
                              hipStream_t stream)
{
    const float* X       = (const float*)d_in[0];
    const int*   pair    = (const int*)d_in[1];
    const float* dij     = (const float*)d_in[2];
    const float* radial  = (const float*)d_in[3];
    const float* charges = (const float*)d_in[4];
    const float* W1  = (const float*)d_in[5];
    const float* b1  = (const float*)d_in[6];
    const float* W2  = (const float*)d_in[7];
    const float* b2  = (const float*)d_in[8];
    const float* W3  = (const float*)d_in[9];
    const float* b3  = (const float*)d_in[10];
    const float* Wl0 = (const float*)d_in[11];
    const float* Wl1 = (const float*)d_in[12];
    const float* Wl2 = (const float*)d_in[13];
    const float* Wl3 = (const float*)d_in[14];
    const float* Wl4 = (const float*)d_in[15];
    const float* Wl5 = (const float*)d_in[16];

    int N = in_sizes[4];
    int E = in_sizes[2];
    int R = 9 * N;
    int nb_gemm = (R + 63) / 64;
    int nb_node4 = (N + 3) / 4;
    int nb_edge = (E + 63) / 64;
    size_t slab9 = (size_t)N * 64 * 9;

    float* A = (float*)d_ws;        // U -> T (in-place GEMM)
    float* B = A + slab9;           // msg -> U2 -> V (in-place chain)
    int* ints   = (int*)(B + slab9);
    int* count  = ints;
    int* off    = count + N;
    int* cursor = off + N + 1;
    int* eOf    = cursor + N;
    int* dstp   = eOf + E;
    int* srcp   = dstp + E;

    hipMemsetAsync(count, 0, (size_t)N * sizeof(int), stream);
    hipMemsetAsync(B, 0, slab9 * sizeof(float), stream);

    k_node_prep<<<nb_node4, 256, 0, stream>>>(X, A, N);
    k_comp_gemm<<<nb_gemm, 256, 0, stream>>>(A, A, Wl0, Wl1, Wl2, R, N);

    k_hist<<<(E + 255) / 256, 256, 0, stream>>>(pair, count, E);
    k_scan<<<1, 1024, 0, stream>>>(count, off, cursor, N, E);
    k_scatter_sort<<<(E + 255) / 256, 256, 0, stream>>>(pair, cursor, eOf, dstp, srcp, E);

    k_edge_sorted<<<nb_edge, 256, 0, stream>>>(radial, dij, eOf, dstp, srcp,
                                               W1, b1, W2, b2, W3, b3, A, B, E, N);

    k_node_mix<<<(N * 64 + 255) / 256, 256, 0, stream>>>(B, A, charges, B, N);
    k_comp_gemm<<<nb_gemm, 256, 0, stream>>>(B, B, Wl3, Wl4, Wl5, R, N);
    k_out<<<(N * 64 + 255) / 256, 256, 0, stream>>>(B, X, charges, (float*)d_out, N);
}

// Round 4
// 1339.115 us; speedup vs baseline: 1.7965x; 1.5965x over previous
//
#include <hip/hip_runtime.h>
#include <math.h>

#ifndef M_PI
#define M_PI 3.14159265358979323846
#endif

// ---------------------------------------------------------------------------
// TensorNet interaction, fp32.
// Compressed irreducible rep per (n,f): u[9] =
//   { lam, a01, a02, a12, s00, s01, s02, s11, s12 }   (s22 = -s00-s11)
// Slab layout for node tensors: [9][N][F] (F contiguous).
//
// Workspace (~120.3 MB):
//   slab A (57.6 MB): U -> (in-place GEMM) -> T
//   slab B (57.6 MB): msg -> (in-place mix) -> U2 -> (in-place GEMM) -> V
//   ints  (~5.1 MB): count[N], off[N+1], cursor[N], eOf[E], dstp[E], srcp[E]
//
// Round-4 change: MLP / comp-GEMM weight accesses made LANE-UNIFORM
// (lane = edge/row, wave = col-group) -> scalar broadcast loads, killing the
// ~220M L2 line-request storm of the per-thread row-major weight reads.
// ---------------------------------------------------------------------------

__device__ __forceinline__ float silu_f(float x) {
    return x / (1.0f + __expf(-x));
}

__device__ __forceinline__ void recon(const float u[9], float M[9]) {
    M[0] =  u[0] + u[4];
    M[1] =  u[1] + u[5];
    M[2] =  u[2] + u[6];
    M[3] = -u[1] + u[5];
    M[4] =  u[0] + u[7];
    M[5] =  u[3] + u[8];
    M[6] = -u[2] + u[6];
    M[7] = -u[3] + u[8];
    M[8] =  u[0] - u[4] - u[7];
}

// ---------------------------------------------------------------------------
// K1: per (n,f): Xn = X/(|X|^2+1), decompose -> U slabs [9][N][64]
// ---------------------------------------------------------------------------
__global__ __launch_bounds__(256) void k_node_prep(
    const float* __restrict__ X, float* __restrict__ U, int N)
{
    __shared__ float s_x[2304];
    int tid = threadIdx.x;
    size_t base = (size_t)blockIdx.x * 2304;
    size_t total = (size_t)N * 576;
    for (int idx = tid; idx < 2304; idx += 256) {
        size_t gi = base + idx;
        s_x[idx] = (gi < total) ? X[gi] : 0.f;
    }
    __syncthreads();
    int w = tid >> 6, f = tid & 63;
    int n = blockIdx.x * 4 + w;
    if (n >= N) return;
    float m[9]; float n2 = 0.f;
#pragma unroll
    for (int i = 0; i < 9; ++i) { m[i] = s_x[w * 576 + f * 9 + i]; n2 += m[i] * m[i]; }
    float inv = 1.0f / (n2 + 1.0f);
#pragma unroll
    for (int i = 0; i < 9; ++i) m[i] *= inv;
    float lam = (m[0] + m[4] + m[8]) * (1.f / 3.f);
    size_t slab = (size_t)N * 64;
    size_t t = (size_t)n * 64 + f;
    U[0 * slab + t] = lam;
    U[1 * slab + t] = 0.5f * (m[1] - m[3]);
    U[2 * slab + t] = 0.5f * (m[2] - m[6]);
    U[3 * slab + t] = 0.5f * (m[5] - m[7]);
    U[4 * slab + t] = m[0] - lam;
    U[5 * slab + t] = 0.5f * (m[1] + m[3]);
    U[6 * slab + t] = 0.5f * (m[2] + m[6]);
    U[7 * slab + t] = m[4] - lam;
    U[8 * slab + t] = 0.5f * (m[5] + m[7]);
}

// ---------------------------------------------------------------------------
// Comp GEMM (in-place safe). out[row][g] = sum_f in[row][f]*Wsel[g][f],
// row = c*N+n. Fast path (block-uniform weight group): lane = row,
// wave = 16-col group, weights via lane-uniform scalar loads.
// ---------------------------------------------------------------------------
__global__ __launch_bounds__(256) void k_comp_gemm(
    const float* in, float* out,
    const float* __restrict__ Wa, const float* __restrict__ Wb,
    const float* __restrict__ Wc, int R, int N)
{
    __shared__ float s_a[64 * 68];   // [k][row] stride 68
    int tid = threadIdx.x;
    int r0 = blockIdx.x * 64;
    for (int idx = tid; idx < 1024; idx += 256) {
        int row = idx >> 4;
        int k4 = (idx & 15) << 2;
        int gr = r0 + row;
        float4 v = make_float4(0.f, 0.f, 0.f, 0.f);
        if (gr < R) v = *(const float4*)(in + (size_t)gr * 64 + k4);
        s_a[(k4 + 0) * 68 + row] = v.x;
        s_a[(k4 + 1) * 68 + row] = v.y;
        s_a[(k4 + 2) * 68 + row] = v.z;
        s_a[(k4 + 3) * 68 + row] = v.w;
    }
    __syncthreads();

    int cA = r0 / N;
    int rlast = min(r0 + 63, R - 1);
    int cB = rlast / N;
    int gA = (cA == 0) ? 0 : (cA < 4 ? 1 : 2);
    int gB = (cB == 0) ? 0 : (cB < 4 ? 1 : 2);

    if (gA == gB) {
        // ---- fast path: lane = row, wave = col-group, scalar weights
        int wv = __builtin_amdgcn_readfirstlane(tid >> 6);
        int lane = tid & 63;
        const float* W = (gA == 0) ? Wa : (gA == 1 ? Wb : Wc);
        float acc[16];
#pragma unroll
        for (int c = 0; c < 16; ++c) acc[c] = 0.f;
#pragma unroll 4
        for (int k = 0; k < 64; ++k) {
            float a = s_a[k * 68 + lane];
#pragma unroll
            for (int c = 0; c < 16; ++c)
                acc[c] += W[(wv * 16 + c) * 64 + k] * a;
        }
        __syncthreads();
        // bounce through LDS for coalesced stores: s_a[col][row]
#pragma unroll
        for (int c = 0; c < 16; ++c)
            s_a[(wv * 16 + c) * 68 + lane] = acc[c];
        __syncthreads();
        for (int idx = tid; idx < 1024; idx += 256) {
            int row = idx >> 4;
            int c4 = (idx & 15) << 2;
            int gr = r0 + row;
            if (gr < R) {
                float4 o = make_float4(s_a[(c4 + 0) * 68 + row],
                                       s_a[(c4 + 1) * 68 + row],
                                       s_a[(c4 + 2) * 68 + row],
                                       s_a[(c4 + 3) * 68 + row]);
                *(float4*)(out + (size_t)gr * 64 + c4) = o;
            }
        }
    } else {
        // ---- rare boundary path (block crosses weight-group boundary)
        int et = tid >> 4, ct = tid & 15;
        int c0 = ct * 4;
        int rbase = r0 + et * 4;
        float4 acc[4];
#pragma unroll
        for (int cc = 0; cc < 4; ++cc) acc[cc] = make_float4(0.f, 0.f, 0.f, 0.f);
        const float* Wi[4];
#pragma unroll
        for (int i = 0; i < 4; ++i) {
            int r = min(rbase + i, R - 1);
            int c = r / N;
            int g = (c == 0) ? 0 : (c < 4 ? 1 : 2);
            Wi[i] = (g == 0) ? Wa : (g == 1 ? Wb : Wc);
        }
        for (int k = 0; k < 64; ++k) {
            float a0 = s_a[k * 68 + et * 4 + 0];
            float a1 = s_a[k * 68 + et * 4 + 1];
            float a2 = s_a[k * 68 + et * 4 + 2];
            float a3 = s_a[k * 68 + et * 4 + 3];
#pragma unroll
            for (int cc = 0; cc < 4; ++cc) {
                acc[cc].x += Wi[0][(c0 + cc) * 64 + k] * a0;
                acc[cc].y += Wi[1][(c0 + cc) * 64 + k] * a1;
                acc[cc].z += Wi[2][(c0 + cc) * 64 + k] * a2;
                acc[cc].w += Wi[3][(c0 + cc) * 64 + k] * a3;
            }
        }
        if (rbase + 0 < R) {
            float4 o = make_float4(acc[0].x, acc[1].x, acc[2].x, acc[3].x);
            *(float4*)(out + (size_t)(rbase + 0) * 64 + c0) = o;
        }
        if (rbase + 1 < R) {
            float4 o = make_float4(acc[0].y, acc[1].y, acc[2].y, acc[3].y);
            *(float4*)(out + (size_t)(rbase + 1) * 64 + c0) = o;
        }
        if (rbase + 2 < R) {
            float4 o = make_float4(acc[0].z, acc[1].z, acc[2].z, acc[3].z);
            *(float4*)(out + (size_t)(rbase + 2) * 64 + c0) = o;
        }
        if (rbase + 3 < R) {
            float4 o = make_float4(acc[0].w, acc[1].w, acc[2].w, acc[3].w);
            *(float4*)(out + (size_t)(rbase + 3) * 64 + c0) = o;
        }
    }
}

// ---------------------------------------------------------------------------
// CSR sort of edges by src: histogram -> scan -> ranked placement.
// ---------------------------------------------------------------------------
__global__ __launch_bounds__(256) void k_hist(
    const int* __restrict__ pair, int* __restrict__ count, int E)
{
    int e = blockIdx.x * 256 + threadIdx.x;
    if (e < E) atomicAdd(&count[pair[e]], 1);
}

__global__ __launch_bounds__(1024) void k_scan(
    const int* __restrict__ count, int* __restrict__ off,
    int* __restrict__ cursor, int N, int E)
{
    __shared__ int s[1024];
    __shared__ int s_carry;
    int tid = threadIdx.x;
    if (tid == 0) s_carry = 0;
    __syncthreads();
    for (int base = 0; base < N; base += 1024) {
        int i = base + tid;
        int v = (i < N) ? count[i] : 0;
        s[tid] = v;
        __syncthreads();
        for (int d = 1; d < 1024; d <<= 1) {
            int t = (tid >= d) ? s[tid - d] : 0;
            __syncthreads();
            s[tid] += t;
            __syncthreads();
        }
        int incl = s[tid];
        int excl = s_carry + incl - v;
        if (i < N) { off[i] = excl; cursor[i] = excl; }
        __syncthreads();
        if (tid == 1023) s_carry += s[1023];
        __syncthreads();
    }
    if (tid == 0) off[N] = E;
}

__global__ __launch_bounds__(256) void k_scatter_sort(
    const int* __restrict__ pair, int* __restrict__ cursor,
    int* __restrict__ eOf, int* __restrict__ dstp, int* __restrict__ srcp, int E)
{
    int e = blockIdx.x * 256 + threadIdx.x;
    if (e < E) {
        int s = pair[e];
        int d = pair[(size_t)E + e];
        int pos = atomicAdd(&cursor[s], 1);
        eOf[pos] = e;
        dstp[pos] = d;
        srcp[pos] = s;
    }
}

// ---------------------------------------------------------------------------
// K2: fused edge MLP (32->64->128->192, SiLU, x cutoff) over SORTED edge
// positions + run-accumulated message pass.
// MLP mapping: lane = edge (64), wave = output col-group (L1:16/L2:32/L3:48
// cols per wave) -> weight reads are wave-uniform scalar broadcasts.
// LDS s_act[c][edge] stride 68 holds activations (lane-contiguous).
// ---------------------------------------------------------------------------
__global__ __launch_bounds__(256) void k_edge_sorted(
    const float* __restrict__ radial, const float* __restrict__ d_ij,
    const int* __restrict__ eOf, const int* __restrict__ dstp,
    const int* __restrict__ srcp,
    const float* __restrict__ W1, const float* __restrict__ b1,
    const float* __restrict__ W2, const float* __restrict__ b2,
    const float* __restrict__ W3, const float* __restrict__ b3,
    const float* __restrict__ T, float* __restrict__ msg,
    int E, int N)
{
    __shared__ float s_act[192 * 68];
    __shared__ float s_C[64];
    __shared__ int s_e[64];
    __shared__ int s_src[64];
    __shared__ int s_dst[64];
    int tid = threadIdx.x;
    int p0 = blockIdx.x * 64;

    if (tid < 64) {
        int p = p0 + tid;
        int e = -1, s = 0, d = 0; float C = 0.f;
        if (p < E) {
            e = eOf[p];
            s = srcp[p];
            d = dstp[p];
            float dd = d_ij[e];
            C = (dd < 5.0f) ? 0.5f * (cosf((float)M_PI * dd * 0.2f) + 1.0f) : 0.0f;
        }
        s_e[tid] = e; s_src[tid] = s; s_dst[tid] = d; s_C[tid] = C;
    }
    __syncthreads();

    {   // stage rbf transposed: s_act[k][j] = radial[eOf[p0+j]*32+k]
        int j = tid >> 2;
        int kk = (tid & 3) * 8;
        int e = s_e[j];
        float4 v0 = make_float4(0.f, 0.f, 0.f, 0.f), v1 = v0;
        if (e >= 0) {
            v0 = *(const float4*)(radial + (size_t)e * 32 + kk);
            v1 = *(const float4*)(radial + (size_t)e * 32 + kk + 4);
        }
        s_act[(kk + 0) * 68 + j] = v0.x;
        s_act[(kk + 1) * 68 + j] = v0.y;
        s_act[(kk + 2) * 68 + j] = v0.z;
        s_act[(kk + 3) * 68 + j] = v0.w;
        s_act[(kk + 4) * 68 + j] = v1.x;
        s_act[(kk + 5) * 68 + j] = v1.y;
        s_act[(kk + 6) * 68 + j] = v1.z;
        s_act[(kk + 7) * 68 + j] = v1.w;
    }
    __syncthreads();

    int wv = __builtin_amdgcn_readfirstlane(tid >> 6);
    int lane = tid & 63;

    // ---- layer 1: 32 -> 64, wave owns cols [wv*16, wv*16+16)
    {
        float acc[16];
#pragma unroll
        for (int c = 0; c < 16; ++c) acc[c] = b1[wv * 16 + c];
#pragma unroll 4
        for (int k = 0; k < 32; ++k) {
            float a = s_act[k * 68 + lane];
#pragma unroll
            for (int c = 0; c < 16; ++c)
                acc[c] += W1[(wv * 16 + c) * 32 + k] * a;
        }
        __syncthreads();
#pragma unroll
        for (int c = 0; c < 16; ++c)
            s_act[(wv * 16 + c) * 68 + lane] = silu_f(acc[c]);
        __syncthreads();
    }

    // ---- layer 2: 64 -> 128, wave owns cols [wv*32, wv*32+32)
    {
        float acc[32];
#pragma unroll
        for (int c = 0; c < 32; ++c) acc[c] = b2[wv * 32 + c];
#pragma unroll 2
        for (int k = 0; k < 64; ++k) {
            float a = s_act[k * 68 + lane];
#pragma unroll
            for (int c = 0; c < 32; ++c)
                acc[c] += W2[(wv * 32 + c) * 64 + k] * a;
        }
        __syncthreads();
#pragma unroll
        for (int c = 0; c < 32; ++c)
            s_act[(wv * 32 + c) * 68 + lane] = silu_f(acc[c]);
        __syncthreads();
    }

    // ---- layer 3: 128 -> 192, wave owns raw cols [wv*48, wv*48+48)
    // raw col o stored at row (o%3)*64 + o/3  (i.e. row cmp*64 + f)
    {
        float acc[48];
#pragma unroll
        for (int c = 0; c < 48; ++c) acc[c] = b3[wv * 48 + c];
#pragma unroll 2
        for (int k = 0; k < 128; ++k) {
            float a = s_act[k * 68 + lane];
#pragma unroll
            for (int c = 0; c < 48; ++c)
                acc[c] += W3[(wv * 48 + c) * 128 + k] * a;
        }
        __syncthreads();
        float C = s_C[lane];
#pragma unroll
        for (int c = 0; c < 48; ++c) {
            int o = wv * 48 + c;
            int row = (o % 3) * 64 + (o / 3);
            s_act[row * 68 + lane] = silu_f(acc[c]) * C;
        }
        __syncthreads();
    }

    // ---- message pass over sorted runs. wave wv -> comps, lane = f.
    {
        size_t slab = (size_t)N * 64;
        int cb = (wv < 3) ? wv * 2 : 7;        // comp base: 0,2,4,7
        int nc = (wv == 2) ? 3 : 2;            // comps per wave
        int c0 = cb, c1 = cb + 1, c2 = cb + 2; // c2 only if nc==3
        int gA = (c0 == 0) ? 0 : ((c0 < 4) ? 1 : 2);
        int gB = (c1 < 4) ? 1 : 2;
        const int rowA = (gA * 64 + lane) * 68;
        const int rowB = (gB * 64 + lane) * 68;
        const int rowC = (2 * 64 + lane) * 68;

        float acc0 = 0.f, acc1 = 0.f, acc2 = 0.f;
        int cur = -1, jstart = 0;
        int jmax = min(64, E - p0);

        auto flush = [&](int jend) {
            if (cur < 0) return;
            long ps = (long)p0 + jstart;
            long pe = (long)p0 + jend;
            bool lb = (ps == 0) || (srcp[ps - 1] != cur);
            bool rb = (pe >= (long)E) || (srcp[pe] != cur);
            size_t b = (size_t)cur * 64 + lane;
            if (lb && rb) {
                msg[(size_t)c0 * slab + b] = acc0;
                msg[(size_t)c1 * slab + b] = acc1;
                if (nc == 3) msg[(size_t)c2 * slab + b] = acc2;
            } else {
                atomicAdd(&msg[(size_t)c0 * slab + b], acc0);
                atomicAdd(&msg[(size_t)c1 * slab + b], acc1);
                if (nc == 3) atomicAdd(&msg[(size_t)c2 * slab + b], acc2);
            }
            acc0 = acc1 = acc2 = 0.f;
        };

        for (int j = 0; j < jmax; ++j) {
            int s = s_src[j];
            if (s != cur) { flush(j); cur = s; jstart = j; }
            int d = s_dst[j];
            size_t bd = (size_t)d * 64 + lane;
            acc0 += s_act[rowA + j] * T[(size_t)c0 * slab + bd];
            acc1 += s_act[rowB + j] * T[(size_t)c1 * slab + bd];
            if (nc == 3) acc2 += s_act[rowC + j] * T[(size_t)c2 * slab + bd];
        }
        flush(jmax);
    }
}

// ---------------------------------------------------------------------------
// K4a (in-place safe): M=recon(msg), Y=recon(T), P=scale*(MY+YM),
// decompose+normalize -> U2
// ---------------------------------------------------------------------------
__global__ __launch_bounds__(256) void k_node_mix(
    const float* msg, const float* __restrict__ T,
    const float* __restrict__ charges, float* U2, int N)
{
    int t = blockIdx.x * 256 + threadIdx.x;
    if (t >= N * 64) return;
    int n = t >> 6;
    size_t slab = (size_t)N * 64;
    float um[9], uy[9];
#pragma unroll
    for (int c = 0; c < 9; ++c) { um[c] = msg[c * slab + t]; uy[c] = T[c * slab + t]; }
    float M[9], Y[9];
    recon(um, M);
    recon(uy, Y);
    float P[9];
#pragma unroll
    for (int i = 0; i < 3; ++i)
#pragma unroll
        for (int j = 0; j < 3; ++j) {
            float s = 0.f;
#pragma unroll
            for (int k = 0; k < 3; ++k)
                s += M[i * 3 + k] * Y[k * 3 + j] + Y[i * 3 + k] * M[k * 3 + j];
            P[i * 3 + j] = s;
        }
    float sc = 1.0f + 0.1f * charges[n];
    float nrm = 0.f;
#pragma unroll
    for (int i = 0; i < 9; ++i) { P[i] *= sc; nrm += P[i] * P[i]; }
    float inv = 1.0f / (nrm + 1.0f);
    float lam = (P[0] + P[4] + P[8]) * (1.f / 3.f);
    U2[0 * slab + t] = lam * inv;
    U2[1 * slab + t] = 0.5f * (P[1] - P[3]) * inv;
    U2[2 * slab + t] = 0.5f * (P[2] - P[6]) * inv;
    U2[3 * slab + t] = 0.5f * (P[5] - P[7]) * inv;
    U2[4 * slab + t] = (P[0] - lam) * inv;
    U2[5 * slab + t] = 0.5f * (P[1] + P[3]) * inv;
    U2[6 * slab + t] = 0.5f * (P[2] + P[6]) * inv;
    U2[7 * slab + t] = (P[4] - lam) * inv;
    U2[8 * slab + t] = 0.5f * (P[5] + P[7]) * inv;
}

// ---------------------------------------------------------------------------
// Output: out = Xn + dX + scale * dX@dX   (Xn recomputed; dX = recon(V))
// ---------------------------------------------------------------------------
__global__ __launch_bounds__(256) void k_out(
    const float* __restrict__ V, const float* __restrict__ X,
    const float* __restrict__ charges, float* __restrict__ out, int N)
{
    __shared__ float s_x[2304];
    __shared__ float s_o[2304];
    int tid = threadIdx.x;
    int blk = blockIdx.x;
    size_t base = (size_t)blk * 2304;
    size_t total = (size_t)N * 576;
    for (int idx = tid; idx < 2304; idx += 256) {
        size_t gi = base + idx;
        s_x[idx] = (gi < total) ? X[gi] : 0.f;
    }
    __syncthreads();
    int t = blk * 256 + tid;
    if (t < N * 64) {
        int n = t >> 6;
        int w = tid >> 6, f = tid & 63;
        size_t slab = (size_t)N * 64;
        float m[9]; float n2 = 0.f;
#pragma unroll
        for (int i = 0; i < 9; ++i) { m[i] = s_x[w * 576 + f * 9 + i]; n2 += m[i] * m[i]; }
        float invn = 1.0f / (n2 + 1.0f);
#pragma unroll
        for (int i = 0; i < 9; ++i) m[i] *= invn;
        float uv[9];
#pragma unroll
        for (int c = 0; c < 9; ++c) uv[c] = V[c * slab + t];
        float dX[9];
        recon(uv, dX);
        float sc = 1.0f + 0.1f * charges[n];
#pragma unroll
        for (int i = 0; i < 3; ++i)
#pragma unroll
            for (int j = 0; j < 3; ++j) {
                float s = 0.f;
#pragma unroll
                for (int k = 0; k < 3; ++k) s += dX[i * 3 + k] * dX[k * 3 + j];
                s_o[w * 576 + f * 9 + i * 3 + j] = m[i * 3 + j] + dX[i * 3 + j] + sc * s;
            }
    }
    __syncthreads();
    for (int idx = tid; idx < 2304; idx += 256) {
        size_t gi = base + idx;
        if (gi < total) out[gi] = s_o[idx];
    }
}

// ---------------------------------------------------------------------------
extern "C" void kernel_launch(void* const* d_in, const int* in_sizes, int n_in,
                              void* d_out, int out_size, void* d_ws, size_t ws_size,
                              hipStream_t stream)
{
    const float* X       = (const float*)d_in[0];
    const int*   pair    = (const int*)d_in[1];
    const float* dij     = (const float*)d_in[2];
    const float* radial  = (const float*)d_in[3];
    const float* charges = (const float*)d_in[4];
    const float* W1  = (const float*)d_in[5];
    const float* b1  = (const float*)d_in[6];
    const float* W2  = (const float*)d_in[7];
    const float* b2  = (const float*)d_in[8];
    const float* W3  = (const float*)d_in[9];
    const float* b3  = (const float*)d_in[10];
    const float* Wl0 = (const float*)d_in[11];
    const float* Wl1 = (const float*)d_in[12];
    const float* Wl2 = (const float*)d_in[13];
    const float* Wl3 = (const float*)d_in[14];
    const float* Wl4 = (const float*)d_in[15];
    const float* Wl5 = (const float*)d_in[16];

    int N = in_sizes[4];
    int E = in_sizes[2];
    int R = 9 * N;
    int nb_gemm = (R + 63) / 64;
    int nb_node4 = (N + 3) / 4;
    int nb_edge = (E + 63) / 64;
    size_t slab9 = (size_t)N * 64 * 9;

    float* A = (float*)d_ws;        // U -> T (in-place GEMM)
    float* B = A + slab9;           // msg -> U2 -> V (in-place chain)
    int* ints   = (int*)(B + slab9);
    int* count  = ints;
    int* off    = count + N;
    int* cursor = off + N + 1;
    int* eOf    = cursor + N;
    int* dstp   = eOf + E;
    int* srcp   = dstp + E;

    hipMemsetAsync(count, 0, (size_t)N * sizeof(int), stream);
    hipMemsetAsync(B, 0, slab9 * sizeof(float), stream);

    k_node_prep<<<nb_node4, 256, 0, stream>>>(X, A, N);
    k_comp_gemm<<<nb_gemm, 256, 0, stream>>>(A, A, Wl0, Wl1, Wl2, R, N);

    k_hist<<<(E + 255) / 256, 256, 0, stream>>>(pair, count, E);
    k_scan<<<1, 1024, 0, stream>>>(count, off, cursor, N, E);
    k_scatter_sort<<<(E + 255) / 256, 256, 0, stream>>>(pair, cursor, eOf, dstp, srcp, E);

    k_edge_sorted<<<nb_edge, 256, 0, stream>>>(radial, dij, eOf, dstp, srcp,
                                               W1, b1, W2, b2, W3, b3, A, B, E, N);

    k_node_mix<<<(N * 64 + 255) / 256, 256, 0, stream>>>(B, A, charges, B, N);
    k_comp_gemm<<<nb_gemm, 256, 0, stream>>>(B, B, Wl3, Wl4, Wl5, R, N);
    k_out<<<(N * 64 + 255) / 256, 256, 0, stream>>>(B, X, charges, (float*)d_out, N);
}